// Round 4
// baseline (82.582 us; speedup 1.0000x reference)
//
#include <hip/hip_runtime.h>
#include <hip/hip_bf16.h>
#include <stdint.h>

// HashedLinear: C[1024][4096] = x[1024][4096] @ w[indx[4096][4096]] + b
#define M_DIM 1024
#define K_DIM 4096
#define N_DIM 4096
#define NW    65536

typedef __bf16 bf16x8 __attribute__((ext_vector_type(8)));
typedef float  f32x4  __attribute__((ext_vector_type(4)));

// float -> bf16 round-to-nearest-even (bit trick; inputs are normal floats)
__device__ __forceinline__ unsigned short f2bf(float f) {
  unsigned u = __float_as_uint(f);
  u += 0x7fffu + ((u >> 16) & 1u);
  return (unsigned short)(u >> 16);
}

__device__ __forceinline__ void load_lds16(const void* g, void* l) {
  __builtin_amdgcn_global_load_lds((const __attribute__((address_space(1))) void*)g,
                                   (__attribute__((address_space(3))) void*)l,
                                   16, 0, 0);
}

// ---- kernel 1: convert x and w to bf16 (stored as ushort) ----
__global__ void prep_kernel(const float* __restrict__ x, const float* __restrict__ w,
                            unsigned short* __restrict__ xb, unsigned short* __restrict__ wb) {
  const int XQ = M_DIM * K_DIM / 4;
  const int WQ = NW / 4;
  int i = blockIdx.x * blockDim.x + threadIdx.x;
  if (i < XQ) {
    float4 v = reinterpret_cast<const float4*>(x)[i];
    ushort4 o;
    o.x = f2bf(v.x); o.y = f2bf(v.y); o.z = f2bf(v.z); o.w = f2bf(v.w);
    reinterpret_cast<ushort4*>(xb)[i] = o;
  } else if (i < XQ + WQ) {
    int j = i - XQ;
    float4 v = reinterpret_cast<const float4*>(w)[j];
    ushort4 o;
    o.x = f2bf(v.x); o.y = f2bf(v.y); o.z = f2bf(v.z); o.w = f2bf(v.w);
    reinterpret_cast<ushort4*>(wb)[j] = o;
  }
}

// ---- kernel 2: gather + transpose with the WHOLE pool staged in LDS ----
// (at its ~15 us streaming roofline: 64 MB indx + 32 MB Bt + pool staging)
__global__ __launch_bounds__(1024)
void gather_kernel(const int* __restrict__ indx,
                   const unsigned short* __restrict__ wb,
                   unsigned short* __restrict__ Bt) {
  __shared__ unsigned short pool[NW];        // 128 KB
  __shared__ unsigned short tile[64][68];    // 8.5 KB
  int t = threadIdx.x;

  {
    const uint4* src = reinterpret_cast<const uint4*>(wb);
    uint4* dst = reinterpret_cast<uint4*>(pool);
#pragma unroll
    for (int i = 0; i < 8; ++i) dst[t + i * 1024] = src[t + i * 1024];
  }

  int r  = t >> 4, cq = t & 15;   // load-phase coords (k-row, n-quad)
  int nn = t >> 4, kq = t & 15;   // write-phase coords (n-row, k-quad)
  int base_tid = blockIdx.x * 16;

  int4 id;
  {
    int k0 = ((base_tid >> 6) << 6), n0 = ((base_tid & 63) << 6);
    id = *reinterpret_cast<const int4*>(indx + (size_t)(k0 + r) * N_DIM + n0 + cq * 4);
  }
  __syncthreads();  // pool ready

  for (int it = 0; it < 16; ++it) {
    int tid = base_tid + it;
    int k0 = ((tid >> 6) << 6), n0 = ((tid & 63) << 6);

    int4 idn = id;
    if (it < 15) {
      int tid2 = tid + 1;
      int k02 = ((tid2 >> 6) << 6), n02 = ((tid2 & 63) << 6);
      idn = *reinterpret_cast<const int4*>(indx + (size_t)(k02 + r) * N_DIM + n02 + cq * 4);
    }

    tile[r][cq * 4 + 0] = pool[id.x];
    tile[r][cq * 4 + 1] = pool[id.y];
    tile[r][cq * 4 + 2] = pool[id.z];
    tile[r][cq * 4 + 3] = pool[id.w];
    __syncthreads();

    ushort4 o;
    o.x = tile[kq * 4 + 0][nn];
    o.y = tile[kq * 4 + 1][nn];
    o.z = tile[kq * 4 + 2][nn];
    o.w = tile[kq * 4 + 3][nn];
    *reinterpret_cast<ushort4*>(Bt + (size_t)(n0 + nn) * K_DIM + k0 + kq * 4) = o;
    __syncthreads();

    id = idn;
  }
}

// ---- kernel 3: bf16 MFMA GEMM, double-buffered 2-phase pipeline ----
// T3-minimal recipe: STAGE(next) issued at top of iter, ds_read+MFMA on cur,
// ONE barrier per K-step (syncthreads' vmcnt0 drain now waits on loads issued
// a full compute-phase earlier).
#define BM 128
#define BN 64
#define BK 64

__global__ __launch_bounds__(256, 2)
void gemm_kernel(const unsigned short* __restrict__ A,   // x bf16 [M][K]
                 const unsigned short* __restrict__ Bt,  // B^T bf16 [N][K]
                 const float* __restrict__ bias,
                 float* __restrict__ C) {                // [M][N] f32
  __shared__ unsigned short As[2][BM * BK];  // 2 x 16 KB
  __shared__ unsigned short Bs[2][BN * BK];  // 2 x 8 KB

  int t = threadIdx.x;
  int lane = t & 63, wid = t >> 6;
  int wm = wid >> 1, wn = wid & 1;        // 2x2 wave grid; wave tile 64x32

  // XCD swizzle (512 blocks, 512%8==0): XCD x gets 64 consecutive logical
  // tiles => 8 consecutive Bt panels (4 MB = one XCD L2) + all 8 M-tiles.
  int bid = blockIdx.x;
  int swz = (bid & 7) * 64 + (bid >> 3);
  int bx = swz & 7, by = swz >> 3;        // bx: M-tile (8), by: N-tile (64)
  int m0 = bx * BM, n0 = by * BN;

  const unsigned short* Ag = A  + (size_t)m0 * K_DIM;
  const unsigned short* Bg = Bt + (size_t)n0 * K_DIM;

  f32x4 acc[4][2];
#pragma unroll
  for (int i = 0; i < 4; ++i)
#pragma unroll
    for (int j = 0; j < 2; ++j)
      acc[i][j] = (f32x4){0.f, 0.f, 0.f, 0.f};

  int fr = lane & 15, hc = lane >> 4;     // frag row, k-half-chunk

  // Staging: LDS linear (global_load_lds requirement); swizzle by permuting
  // the GLOBAL source 16B-chunk: LDS slot s holds global chunk s^(r&7).
#define STAGE(buf, kb)                                                        \
  do {                                                                        \
    _Pragma("unroll")                                                         \
    for (int i_ = 0; i_ < 4; ++i_) {                                          \
      int c_ = t + i_ * 256;                                                  \
      int r_ = c_ >> 3, s_ = c_ & 7;                                          \
      load_lds16(Ag + (size_t)r_ * K_DIM + (kb) + ((s_ ^ (r_ & 7)) << 3),     \
                 (char*)As[buf] + c_ * 16);                                   \
    }                                                                         \
    _Pragma("unroll")                                                         \
    for (int i_ = 0; i_ < 2; ++i_) {                                          \
      int c_ = t + i_ * 256;                                                  \
      int r_ = c_ >> 3, s_ = c_ & 7;                                          \
      load_lds16(Bg + (size_t)r_ * K_DIM + (kb) + ((s_ ^ (r_ & 7)) << 3),     \
                 (char*)Bs[buf] + c_ * 16);                                   \
    }                                                                         \
  } while (0)

  STAGE(0, 0);
  __syncthreads();  // vmcnt(0) drain: buf0 ready

  const int NT = K_DIM / BK;  // 64
  for (int kt = 0; kt < NT; ++kt) {
    int cur = kt & 1;
    if (kt + 1 < NT) STAGE(cur ^ 1, (kt + 1) * BK);  // issue next-tile loads EARLY

#pragma unroll
    for (int kk = 0; kk < 2; ++kk) {
      bf16x8 af[4], bfv[2];
#pragma unroll
      for (int mi = 0; mi < 4; ++mi) {
        int row = wm * 64 + mi * 16 + fr;
        int q = (hc + kk * 4) ^ (row & 7);   // logical chunk ^ row swizzle
        af[mi] = *reinterpret_cast<const bf16x8*>((char*)As[cur] + row * 128 + q * 16);
      }
#pragma unroll
      for (int ni = 0; ni < 2; ++ni) {
        int row = wn * 32 + ni * 16 + fr;
        int q = (hc + kk * 4) ^ (row & 7);
        bfv[ni] = *reinterpret_cast<const bf16x8*>((char*)Bs[cur] + row * 128 + q * 16);
      }
#pragma unroll
      for (int mi = 0; mi < 4; ++mi)
#pragma unroll
        for (int ni = 0; ni < 2; ++ni)
          acc[mi][ni] = __builtin_amdgcn_mfma_f32_16x16x32_bf16(af[mi], bfv[ni], acc[mi][ni], 0, 0, 0);
    }
    __syncthreads();  // single barrier/K-step: drains next-tile stage (issued
                      // ~a full compute phase ago) + all waves' frag reads done
  }

  // epilogue: C/D layout col = lane&15, row = (lane>>4)*4 + j  (m89-verified)
  int fq = lane >> 4;
#pragma unroll
  for (int ni = 0; ni < 2; ++ni) {
    int gc = n0 + wn * 32 + ni * 16 + fr;
    float bv = bias[gc];
#pragma unroll
    for (int mi = 0; mi < 4; ++mi) {
      int gr = m0 + wm * 64 + mi * 16 + fq * 4;
#pragma unroll
      for (int j = 0; j < 4; ++j)
        C[(size_t)(gr + j) * N_DIM + gc] = acc[mi][ni][j] + bv;
    }
  }
#undef STAGE
}

extern "C" void kernel_launch(void* const* d_in, const int* in_sizes, int n_in,
                              void* d_out, int out_size, void* d_ws, size_t ws_size,
                              hipStream_t stream) {
  const float* x    = (const float*)d_in[0];
  const float* w    = (const float*)d_in[1];
  const float* b    = (const float*)d_in[2];
  const int*   indx = (const int*)d_in[3];
  float* out = (float*)d_out;

  // workspace: xb (8 MB) | wb (128 KB) | Bt (32 MB)
  unsigned short* xb = (unsigned short*)d_ws;
  unsigned short* wb = xb + (size_t)M_DIM * K_DIM;
  unsigned short* Bt = wb + NW;

  int prep_total = (M_DIM * K_DIM + NW) / 4;
  prep_kernel<<<(prep_total + 255) / 256, 256, 0, stream>>>(x, w, xb, wb);
  gather_kernel<<<256, 1024, 0, stream>>>(indx, wb, Bt);
  gemm_kernel<<<512, 256, 0, stream>>>(xb, Bt, b, out);
}

// Round 5
// 81.904 us; speedup vs baseline: 1.0083x; 1.0083x over previous
//
#include <hip/hip_runtime.h>
#include <hip/hip_bf16.h>
#include <stdint.h>

// HashedLinear: C[1024][4096] = x[1024][4096] @ w[indx[4096][4096]] + b
#define M_DIM 1024
#define K_DIM 4096
#define N_DIM 4096
#define NW    65536

typedef __bf16 bf16x8 __attribute__((ext_vector_type(8)));
typedef float  f32x4  __attribute__((ext_vector_type(4)));

// float -> bf16 round-to-nearest-even (bit trick; inputs are normal floats)
__device__ __forceinline__ unsigned short f2bf(float f) {
  unsigned u = __float_as_uint(f);
  u += 0x7fffu + ((u >> 16) & 1u);
  return (unsigned short)(u >> 16);
}

__device__ __forceinline__ void load_lds16(const void* g, void* l) {
  __builtin_amdgcn_global_load_lds((const __attribute__((address_space(1))) void*)g,
                                   (__attribute__((address_space(3))) void*)l,
                                   16, 0, 0);
}

// ---- kernel 1: convert x and w to bf16 (stored as ushort) ----
__global__ void prep_kernel(const float* __restrict__ x, const float* __restrict__ w,
                            unsigned short* __restrict__ xb, unsigned short* __restrict__ wb) {
  const int XQ = M_DIM * K_DIM / 4;
  const int WQ = NW / 4;
  int i = blockIdx.x * blockDim.x + threadIdx.x;
  if (i < XQ) {
    float4 v = reinterpret_cast<const float4*>(x)[i];
    ushort4 o;
    o.x = f2bf(v.x); o.y = f2bf(v.y); o.z = f2bf(v.z); o.w = f2bf(v.w);
    reinterpret_cast<ushort4*>(xb)[i] = o;
  } else if (i < XQ + WQ) {
    int j = i - XQ;
    float4 v = reinterpret_cast<const float4*>(w)[j];
    ushort4 o;
    o.x = f2bf(v.x); o.y = f2bf(v.y); o.z = f2bf(v.z); o.w = f2bf(v.w);
    reinterpret_cast<ushort4*>(wb)[j] = o;
  }
}

// ---- kernel 2: gather + transpose with the WHOLE pool staged in LDS ----
// (at its ~15 us streaming roofline: 64 MB indx + 32 MB Bt + pool staging)
__global__ __launch_bounds__(1024)
void gather_kernel(const int* __restrict__ indx,
                   const unsigned short* __restrict__ wb,
                   unsigned short* __restrict__ Bt) {
  __shared__ unsigned short pool[NW];        // 128 KB
  __shared__ unsigned short tile[64][68];    // 8.5 KB
  int t = threadIdx.x;

  {
    const uint4* src = reinterpret_cast<const uint4*>(wb);
    uint4* dst = reinterpret_cast<uint4*>(pool);
#pragma unroll
    for (int i = 0; i < 8; ++i) dst[t + i * 1024] = src[t + i * 1024];
  }

  int r  = t >> 4, cq = t & 15;   // load-phase coords (k-row, n-quad)
  int nn = t >> 4, kq = t & 15;   // write-phase coords (n-row, k-quad)
  int base_tid = blockIdx.x * 16;

  int4 id;
  {
    int k0 = ((base_tid >> 6) << 6), n0 = ((base_tid & 63) << 6);
    id = *reinterpret_cast<const int4*>(indx + (size_t)(k0 + r) * N_DIM + n0 + cq * 4);
  }
  __syncthreads();  // pool ready

  for (int it = 0; it < 16; ++it) {
    int tid = base_tid + it;
    int k0 = ((tid >> 6) << 6), n0 = ((tid & 63) << 6);

    int4 idn = id;
    if (it < 15) {
      int tid2 = tid + 1;
      int k02 = ((tid2 >> 6) << 6), n02 = ((tid2 & 63) << 6);
      idn = *reinterpret_cast<const int4*>(indx + (size_t)(k02 + r) * N_DIM + n02 + cq * 4);
    }

    tile[r][cq * 4 + 0] = pool[id.x];
    tile[r][cq * 4 + 1] = pool[id.y];
    tile[r][cq * 4 + 2] = pool[id.z];
    tile[r][cq * 4 + 3] = pool[id.w];
    __syncthreads();

    ushort4 o;
    o.x = tile[kq * 4 + 0][nn];
    o.y = tile[kq * 4 + 1][nn];
    o.z = tile[kq * 4 + 2][nn];
    o.w = tile[kq * 4 + 3][nn];
    *reinterpret_cast<ushort4*>(Bt + (size_t)(n0 + nn) * K_DIM + k0 + kq * 4) = o;
    __syncthreads();

    id = idn;
  }
}

// ---- kernel 3: bf16 MFMA GEMM, dbuf 2-phase with COUNTED vmcnt (T4) ----
// Key fix vs prior round: never drain vmcnt to 0 in the main loop.
// s_waitcnt vmcnt(6) waits only for STAGE(cur) (issued one compute-phase
// earlier); STAGE(cur^1)'s 6 loads stay in flight across the raw s_barrier.
#define BM 128
#define BN 64
#define BK 64

__global__ __launch_bounds__(256, 2)
void gemm_kernel(const unsigned short* __restrict__ A,   // x bf16 [M][K]
                 const unsigned short* __restrict__ Bt,  // B^T bf16 [N][K]
                 const float* __restrict__ bias,
                 float* __restrict__ C) {                // [M][N] f32
  __shared__ unsigned short As[2][BM * BK];  // 2 x 16 KB
  __shared__ unsigned short Bs[2][BN * BK];  // 2 x 8 KB

  int t = threadIdx.x;
  int lane = t & 63, wid = t >> 6;
  int wm = wid >> 1, wn = wid & 1;        // 2x2 wave grid; wave tile 64x32

  // XCD swizzle (512 blocks, 512%8==0)
  int bid = blockIdx.x;
  int swz = (bid & 7) * 64 + (bid >> 3);
  int bx = swz & 7, by = swz >> 3;        // bx: M-tile (8), by: N-tile (64)
  int m0 = bx * BM, n0 = by * BN;

  const unsigned short* Ag = A  + (size_t)m0 * K_DIM;
  const unsigned short* Bg = Bt + (size_t)n0 * K_DIM;

  f32x4 acc[4][2];
#pragma unroll
  for (int i = 0; i < 4; ++i)
#pragma unroll
    for (int j = 0; j < 2; ++j)
      acc[i][j] = (f32x4){0.f, 0.f, 0.f, 0.f};

  int fr = lane & 15, hc = lane >> 4;     // frag row, k-half-chunk

  // Staging: LDS linear (global_load_lds requirement); swizzle by permuting
  // the GLOBAL source 16B-chunk: LDS slot s holds global chunk s^(r&7).
#define STAGE(buf, kb)                                                        \
  do {                                                                        \
    _Pragma("unroll")                                                         \
    for (int i_ = 0; i_ < 4; ++i_) {                                          \
      int c_ = t + i_ * 256;                                                  \
      int r_ = c_ >> 3, s_ = c_ & 7;                                          \
      load_lds16(Ag + (size_t)r_ * K_DIM + (kb) + ((s_ ^ (r_ & 7)) << 3),     \
                 (char*)As[buf] + c_ * 16);                                   \
    }                                                                         \
    _Pragma("unroll")                                                         \
    for (int i_ = 0; i_ < 2; ++i_) {                                          \
      int c_ = t + i_ * 256;                                                  \
      int r_ = c_ >> 3, s_ = c_ & 7;                                          \
      load_lds16(Bg + (size_t)r_ * K_DIM + (kb) + ((s_ ^ (r_ & 7)) << 3),     \
                 (char*)Bs[buf] + c_ * 16);                                   \
    }                                                                         \
  } while (0)

  STAGE(0, 0);  // 6 loads in flight

  const int NT = K_DIM / BK;  // 64
  for (int kt = 0; kt < NT; ++kt) {
    int cur = kt & 1;
    if (kt + 1 < NT) {
      STAGE(cur ^ 1, (kt + 1) * BK);                    // 12 in flight
      asm volatile("s_waitcnt vmcnt(6)" ::: "memory");  // oldest 6 (=cur) done
    } else {
      asm volatile("s_waitcnt vmcnt(0)" ::: "memory");  // final tile: drain
    }
    __builtin_amdgcn_sched_barrier(0);
    __builtin_amdgcn_s_barrier();   // raw: no vmcnt(0) drain attached
    __builtin_amdgcn_sched_barrier(0);

#pragma unroll
    for (int kk = 0; kk < 2; ++kk) {
      bf16x8 af[4], bfv[2];
#pragma unroll
      for (int mi = 0; mi < 4; ++mi) {
        int row = wm * 64 + mi * 16 + fr;
        int q = (hc + kk * 4) ^ (row & 7);   // logical chunk ^ row swizzle
        af[mi] = *reinterpret_cast<const bf16x8*>((char*)As[cur] + row * 128 + q * 16);
      }
#pragma unroll
      for (int ni = 0; ni < 2; ++ni) {
        int row = wn * 32 + ni * 16 + fr;
        int q = (hc + kk * 4) ^ (row & 7);
        bfv[ni] = *reinterpret_cast<const bf16x8*>((char*)Bs[cur] + row * 128 + q * 16);
      }
#pragma unroll
      for (int mi = 0; mi < 4; ++mi)
#pragma unroll
        for (int ni = 0; ni < 2; ++ni)
          acc[mi][ni] = __builtin_amdgcn_mfma_f32_16x16x32_bf16(af[mi], bfv[ni], acc[mi][ni], 0, 0, 0);
    }
    __builtin_amdgcn_sched_barrier(0);
    __builtin_amdgcn_s_barrier();   // all waves done reading cur; next iter
    __builtin_amdgcn_sched_barrier(0);  // may overwrite it (ds_reads already
                                        // consumed via lgkmcnt before MFMAs)
  }

  // epilogue: C/D layout col = lane&15, row = (lane>>4)*4 + j  (m89-verified)
  int fq = lane >> 4;
#pragma unroll
  for (int ni = 0; ni < 2; ++ni) {
    int gc = n0 + wn * 32 + ni * 16 + fr;
    float bv = bias[gc];
#pragma unroll
    for (int mi = 0; mi < 4; ++mi) {
      int gr = m0 + wm * 64 + mi * 16 + fq * 4;
#pragma unroll
      for (int j = 0; j < 4; ++j)
        C[(size_t)(gr + j) * N_DIM + gc] = acc[mi][ni][j] + bv;
    }
  }
#undef STAGE
}

extern "C" void kernel_launch(void* const* d_in, const int* in_sizes, int n_in,
                              void* d_out, int out_size, void* d_ws, size_t ws_size,
                              hipStream_t stream) {
  const float* x    = (const float*)d_in[0];
  const float* w    = (const float*)d_in[1];
  const float* b    = (const float*)d_in[2];
  const int*   indx = (const int*)d_in[3];
  float* out = (float*)d_out;

  // workspace: xb (8 MB) | wb (128 KB) | Bt (32 MB)
  unsigned short* xb = (unsigned short*)d_ws;
  unsigned short* wb = xb + (size_t)M_DIM * K_DIM;
  unsigned short* Bt = wb + NW;

  int prep_total = (M_DIM * K_DIM + NW) / 4;
  prep_kernel<<<(prep_total + 255) / 256, 256, 0, stream>>>(x, w, xb, wb);
  gather_kernel<<<256, 1024, 0, stream>>>(indx, wb, Bt);
  gemm_kernel<<<512, 256, 0, stream>>>(xb, Bt, b, out);
}